// Round 1
// baseline (210.075 us; speedup 1.0000x reference)
//
#include <hip/hip_runtime.h>
#include <hip/hip_bf16.h>

// MatchingLayer: out[b,i,j] = <l2norm(a[b,i,:]*w), l2norm(b[b,j,:]*w)>
// B=16, L=1024, D=1024.  Two kernels:
//  1) normalize a*w, b*w rows -> bf16 in workspace
//  2) batched bf16 MFMA GEMM (A * B^T), fp32 out

typedef __bf16 bf16x8 __attribute__((ext_vector_type(8)));
typedef float f32x4 __attribute__((ext_vector_type(4)));

__device__ __forceinline__ unsigned short f2bf(float f) {
  __hip_bfloat16 h = __float2bfloat16(f);
  return *reinterpret_cast<unsigned short*>(&h);
}

__device__ __forceinline__ void gload16(const void* g, void* lds) {
  __builtin_amdgcn_global_load_lds(
      (const __attribute__((address_space(1))) unsigned int*)g,
      (__attribute__((address_space(3))) unsigned int*)lds,
      16, 0, 0);
}

// ---------------- Kernel 1: row l2-normalize of x*w, output bf16 ----------
// one wave per row (1024 f32), 4 waves/block, 32768 rows total
__global__ void __launch_bounds__(256)
norm_scale_kernel(const float* __restrict__ a, const float* __restrict__ b,
                  const float* __restrict__ w, unsigned short* __restrict__ ra,
                  unsigned short* __restrict__ rb) {
  const int wave = threadIdx.x >> 6;
  const int lane = threadIdx.x & 63;
  const int row = blockIdx.x * 4 + wave;  // 0..32767

  const float* src;
  unsigned short* dst;
  if (row < 16384) {
    src = a + (size_t)row * 1024;
    dst = ra + (size_t)row * 1024;
  } else {
    src = b + (size_t)(row - 16384) * 1024;
    dst = rb + (size_t)(row - 16384) * 1024;
  }

  float4 x[4];
  float sq = 0.f;
#pragma unroll
  for (int c = 0; c < 4; ++c) {
    float4 xv = *(const float4*)(src + c * 256 + lane * 4);
    float4 wv = *(const float4*)(w + c * 256 + lane * 4);
    xv.x *= wv.x; xv.y *= wv.y; xv.z *= wv.z; xv.w *= wv.w;
    x[c] = xv;
    sq += xv.x * xv.x + xv.y * xv.y + xv.z * xv.z + xv.w * xv.w;
  }
#pragma unroll
  for (int off = 32; off > 0; off >>= 1) sq += __shfl_xor(sq, off);
  const float s = rsqrtf(fmaxf(sq, 1e-12f));
#pragma unroll
  for (int c = 0; c < 4; ++c) {
    ushort4 u;
    u.x = f2bf(x[c].x * s);
    u.y = f2bf(x[c].y * s);
    u.z = f2bf(x[c].z * s);
    u.w = f2bf(x[c].w * s);
    *(ushort4*)(dst + c * 256 + lane * 4) = u;
  }
}

// ---------------- Kernel 2: batched GEMM C = RA * RB^T ------------------
// 128x128 tile, BK=32, 256 threads (4 waves, 2x2), 16x16x32 bf16 MFMA,
// global_load_lds width-16 staging, double-buffered LDS, XCD swizzle.
__global__ void __launch_bounds__(256, 3)
gemm_bt_kernel(const unsigned short* __restrict__ RA,
               const unsigned short* __restrict__ RB,
               float* __restrict__ C) {
  constexpr int D = 1024;
  __shared__ char lds[32768];  // [2 bufs][A:8192 | B:8192]

  const int t = threadIdx.x;
  const int w = t >> 6;
  const int l = t & 63;
  const int wr = w >> 1, wc = w & 1;

  // bijective XCD-chunk swizzle: each XCD gets a contiguous 128-WG chunk
  const int orig = (int)blockIdx.x;
  const int wgid = (orig & 7) * ((int)gridDim.x >> 3) + (orig >> 3);
  const int batch = wgid >> 6;
  const int tile = wgid & 63;
  const int brow = (tile >> 3) << 7;
  const int bcol = (tile & 7) << 7;

  const unsigned short* Ab = RA + ((size_t)batch << 20);
  const unsigned short* Bb = RB + ((size_t)batch << 20);

  // staging sources: thread t covers 16B at lds row (t>>2)+c*64, col (t&3)*8
  const unsigned short* ga0 = Ab + (size_t)(brow + (t >> 2)) * D + (t & 3) * 8;
  const unsigned short* ga1 = ga0 + (size_t)64 * D;
  const unsigned short* gb0 = Bb + (size_t)(bcol + (t >> 2)) * D + (t & 3) * 8;
  const unsigned short* gb1 = gb0 + (size_t)64 * D;

  char* sA = (char*)lds;
  const int wA = w << 10;  // wave-uniform LDS base offset (1024B per wave)

  // per-lane fragment read byte offsets (row stride 64B = 32 bf16)
  const int rdA = ((wr << 6) + (l & 15)) * 64 + ((l >> 4) << 4);
  const int rdB = 8192 + ((wc << 6) + (l & 15)) * 64 + ((l >> 4) << 4);

  f32x4 acc[4][4] = {};

#define STAGE(BOFF)                                  \
  do {                                               \
    gload16(ga0, sA + (BOFF) + wA);                  \
    gload16(ga1, sA + (BOFF) + 4096 + wA);           \
    gload16(gb0, sA + (BOFF) + 8192 + wA);           \
    gload16(gb1, sA + (BOFF) + 12288 + wA);          \
    ga0 += 32; ga1 += 32; gb0 += 32; gb1 += 32;      \
  } while (0)

  STAGE(0);
  asm volatile("s_waitcnt vmcnt(0)" ::: "memory");
  __syncthreads();

  int bufoff = 0;
#pragma unroll 1
  for (int kt = 0; kt < 31; ++kt) {
    const int nbuf = bufoff ^ 16384;
    STAGE(nbuf);

    bf16x8 af[4], bfr[4];
#pragma unroll
    for (int m = 0; m < 4; ++m)
      af[m] = *(const bf16x8*)(sA + bufoff + rdA + m * 1024);
#pragma unroll
    for (int n = 0; n < 4; ++n)
      bfr[n] = *(const bf16x8*)(sA + bufoff + rdB + n * 1024);

#pragma unroll
    for (int m = 0; m < 4; ++m)
#pragma unroll
      for (int n = 0; n < 4; ++n)
        acc[m][n] = __builtin_amdgcn_mfma_f32_16x16x32_bf16(af[m], bfr[n],
                                                            acc[m][n], 0, 0, 0);
    __syncthreads();
    bufoff = nbuf;
  }

  {  // last tile (no prefetch)
    bf16x8 af[4], bfr[4];
#pragma unroll
    for (int m = 0; m < 4; ++m)
      af[m] = *(const bf16x8*)(sA + bufoff + rdA + m * 1024);
#pragma unroll
    for (int n = 0; n < 4; ++n)
      bfr[n] = *(const bf16x8*)(sA + bufoff + rdB + n * 1024);
#pragma unroll
    for (int m = 0; m < 4; ++m)
#pragma unroll
      for (int n = 0; n < 4; ++n)
        acc[m][n] = __builtin_amdgcn_mfma_f32_16x16x32_bf16(af[m], bfr[n],
                                                            acc[m][n], 0, 0, 0);
  }
#undef STAGE

  // epilogue: C/D layout col=lane&15, row=(lane>>4)*4+reg
  float* Cb = C + ((size_t)batch << 20);
  const int crow0 = brow + (wr << 6) + ((l >> 4) << 2);
  const int ccol0 = bcol + (wc << 6) + (l & 15);
#pragma unroll
  for (int m = 0; m < 4; ++m)
#pragma unroll
    for (int n = 0; n < 4; ++n) {
#pragma unroll
      for (int r = 0; r < 4; ++r) {
        Cb[(size_t)(crow0 + m * 16 + r) * 1024 + ccol0 + n * 16] = acc[m][n][r];
      }
    }
}

extern "C" void kernel_launch(void* const* d_in, const int* in_sizes, int n_in,
                              void* d_out, int out_size, void* d_ws, size_t ws_size,
                              hipStream_t stream) {
  const float* a = (const float*)d_in[0];
  const float* b = (const float*)d_in[1];
  const float* w = (const float*)d_in[2];
  float* out = (float*)d_out;

  unsigned short* ra = (unsigned short*)d_ws;                    // 16M bf16
  unsigned short* rb = ra + (size_t)16 * 1024 * 1024;            // 16M bf16

  norm_scale_kernel<<<8192, 256, 0, stream>>>(a, b, w, ra, rb);
  gemm_bt_kernel<<<1024, 256, 0, stream>>>(ra, rb, out);
}

// Round 3
// 203.983 us; speedup vs baseline: 1.0299x; 1.0299x over previous
//
#include <hip/hip_runtime.h>
#include <hip/hip_bf16.h>

// MatchingLayer: out[b,i,j] = <l2norm(a[b,i,:]*w), l2norm(b[b,j,:]*w)>
// B=16, L=1024, D=1024.
//  K1: normalize a*w, b*w rows -> bf16 in workspace (unchanged from R1, passed)
//  K2: batched bf16 GEMM, 256x256 tile, BK=64, 8 waves, 8-phase schedule
//      (T2 swizzle + T3/T4 counted vmcnt + T5 setprio), fp32 out.

typedef __bf16 bf16x8 __attribute__((ext_vector_type(8)));
typedef float f32x4 __attribute__((ext_vector_type(4)));

__device__ __forceinline__ unsigned short f2bf(float f) {
  __hip_bfloat16 h = __float2bfloat16(f);
  return *reinterpret_cast<unsigned short*>(&h);
}

__device__ __forceinline__ void gload16(const void* g, void* ldsp) {
  __builtin_amdgcn_global_load_lds(
      (const __attribute__((address_space(1))) unsigned int*)g,
      (__attribute__((address_space(3))) unsigned int*)ldsp,
      16, 0, 0);
}

// ---------------- Kernel 1: row l2-normalize of x*w, output bf16 ----------
__global__ void __launch_bounds__(256)
norm_scale_kernel(const float* __restrict__ a, const float* __restrict__ b,
                  const float* __restrict__ w, unsigned short* __restrict__ ra,
                  unsigned short* __restrict__ rb) {
  const int wave = threadIdx.x >> 6;
  const int lane = threadIdx.x & 63;
  const int row = blockIdx.x * 4 + wave;  // 0..32767

  const float* src;
  unsigned short* dst;
  if (row < 16384) {
    src = a + (size_t)row * 1024;
    dst = ra + (size_t)row * 1024;
  } else {
    src = b + (size_t)(row - 16384) * 1024;
    dst = rb + (size_t)(row - 16384) * 1024;
  }

  float4 x[4];
  float sq = 0.f;
#pragma unroll
  for (int c = 0; c < 4; ++c) {
    float4 xv = *(const float4*)(src + c * 256 + lane * 4);
    float4 wv = *(const float4*)(w + c * 256 + lane * 4);
    xv.x *= wv.x; xv.y *= wv.y; xv.z *= wv.z; xv.w *= wv.w;
    x[c] = xv;
    sq += xv.x * xv.x + xv.y * xv.y + xv.z * xv.z + xv.w * xv.w;
  }
#pragma unroll
  for (int off = 32; off > 0; off >>= 1) sq += __shfl_xor(sq, off);
  const float s = rsqrtf(fmaxf(sq, 1e-12f));
#pragma unroll
  for (int c = 0; c < 4; ++c) {
    ushort4 u;
    u.x = f2bf(x[c].x * s);
    u.y = f2bf(x[c].y * s);
    u.z = f2bf(x[c].z * s);
    u.w = f2bf(x[c].w * s);
    *(ushort4*)(dst + c * 256 + lane * 4) = u;
  }
}

// ---------------- Kernel 2: 256x256 8-phase batched GEMM ------------------
// LDS per buffer: A 256x64 bf16 (32KB) + B 256x64 (32KB); 2 buffers = 128KB.
// A half h holds global tile-rows via grow = ((rr>>6)<<7) + h*64 + (rr&63),
// rr = row within half.  B half h: grow = ((rr>>5)<<6) + h*32 + (rr&31).
// Swizzle: 16B chunk position = chunk ^ (row&7); applied on global src
// (stage) and on ds_read addr; LDS dest of global_load_lds stays linear.
__global__ void __launch_bounds__(512, 2)
gemm8_kernel(const unsigned short* __restrict__ RA,
             const unsigned short* __restrict__ RB,
             float* __restrict__ C) {
  __shared__ __align__(16) char lds[131072];

  const int t = threadIdx.x;
  const int w = t >> 6, l = t & 63;
  const int wr = w >> 2, wc = w & 3;    // 2 x 4 wave grid
  const int l4 = l & 15, lh = l >> 4;
  const int lr = l >> 3;                // staging row-within-8 = swizzle key
  const int lch = (l & 7) ^ lr;         // staged global 16B-chunk index

  // bijective XCD swizzle (256 WGs, 256%8==0)
  const int orig = (int)blockIdx.x;
  const int wgid = (orig & 7) * 32 + (orig >> 3);
  const int batch = wgid >> 4;
  const int tile = wgid & 15;
  const int brow_t = (tile >> 2) << 8;
  const int bcol_t = (tile & 3) << 8;

  const unsigned short* Ab = RA + ((size_t)batch << 20) + (size_t)brow_t * 1024;
  const unsigned short* Bb = RB + ((size_t)batch << 20) + (size_t)bcol_t * 1024;

  int aoff[2][2], boff[2][2];
#pragma unroll
  for (int h = 0; h < 2; ++h)
#pragma unroll
    for (int g = 0; g < 2; ++g) {
      const int rr = w * 16 + g * 8 + lr;                 // row within half
      const int ga = ((rr >> 6) << 7) + h * 64 + (rr & 63);
      const int gb = ((rr >> 5) << 6) + h * 32 + (rr & 31);
      aoff[h][g] = ga * 1024 + lch * 8;
      boff[h][g] = gb * 1024 + lch * 8;
    }
  const int stgw = w * 2048;

  // fragment-read addressing (region-relative bytes)
  const int arow = (wr * 64 + l4) * 128;
  const int brow = (wc * 32 + l4) * 128;
  int csw[2];
  csw[0] = ((0 + lh) ^ (l & 7)) * 16;
  csw[1] = ((4 + lh) ^ (l & 7)) * 16;

  f32x4 acc[8][4] = {};
  bf16x8 af[4][2], bq0[2][2], bq1[2][2];

#define STAGE_A(h, tau)                                                   \
  do {                                                                    \
    char* _d = lds + ((tau) & 1) * 65536 + (h) * 16384 + stgw;            \
    gload16(Ab + (size_t)aoff[h][0] + (size_t)(tau) * 64, _d);            \
    gload16(Ab + (size_t)aoff[h][1] + (size_t)(tau) * 64, _d + 1024);     \
  } while (0)
#define STAGE_B(h, tau)                                                   \
  do {                                                                    \
    char* _d = lds + ((tau) & 1) * 65536 + 32768 + (h) * 16384 + stgw;    \
    gload16(Bb + (size_t)boff[h][0] + (size_t)(tau) * 64, _d);            \
    gload16(Bb + (size_t)boff[h][1] + (size_t)(tau) * 64, _d + 1024);     \
  } while (0)
#define LDA(mh, bufbase)                                                  \
  _Pragma("unroll") for (int mm = 0; mm < 4; ++mm)                        \
  _Pragma("unroll") for (int ks = 0; ks < 2; ++ks)                        \
      af[mm][ks] = *(const bf16x8*)((bufbase) + (mh) * 16384 + arow +     \
                                    mm * 2048 + csw[ks]);
#define LDB(dst, nh, bufbase)                                             \
  _Pragma("unroll") for (int nn = 0; nn < 2; ++nn)                        \
  _Pragma("unroll") for (int ks = 0; ks < 2; ++ks)                        \
      dst[nn][ks] = *(const bf16x8*)((bufbase) + 32768 + (nh) * 16384 +   \
                                     brow + nn * 2048 + csw[ks]);
#define MQ(mh, nh, bsrc)                                                  \
  _Pragma("unroll") for (int mm = 0; mm < 4; ++mm)                        \
  _Pragma("unroll") for (int nn = 0; nn < 2; ++nn)                        \
  _Pragma("unroll") for (int ks = 0; ks < 2; ++ks)                        \
      acc[(mh) * 4 + mm][(nh) * 2 + nn] =                                 \
          __builtin_amdgcn_mfma_f32_16x16x32_bf16(                        \
              af[mm][ks], bsrc[nn][ks], acc[(mh) * 4 + mm][(nh) * 2 + nn],\
              0, 0, 0);
#define PHASE_PRE()                                                       \
  __builtin_amdgcn_s_barrier();                                           \
  asm volatile("s_waitcnt lgkmcnt(0)" ::: "memory");                      \
  __builtin_amdgcn_sched_barrier(0);                                      \
  __builtin_amdgcn_s_setprio(1)
#define PHASE_POST()                                                      \
  __builtin_amdgcn_s_setprio(0);                                          \
  __builtin_amdgcn_s_barrier()

  const char* b0 = lds;
  const char* b1 = lds + 65536;

  // prologue: tile0 fully, tile1 3/4 staged; wait tile0 (14 issued -> 6 left)
  STAGE_A(0, 0); STAGE_B(0, 0); STAGE_B(1, 0); STAGE_A(1, 0);
  STAGE_A(0, 1); STAGE_B(0, 1); STAGE_B(1, 1);
  asm volatile("s_waitcnt vmcnt(6)" ::: "memory");
  __builtin_amdgcn_s_barrier();

#pragma unroll 1
  for (int i = 0; i < 7; ++i) {
    const int u = 2 * i;
    // p1: q00(u); stage Ah1(u+1) [completes tile u+1]
    LDA(0, b0); LDB(bq0, 0, b0); STAGE_A(1, u + 1);
    PHASE_PRE(); MQ(0, 0, bq0); PHASE_POST();
    // p2: q01(u); stage Ah0(u+2) (Ah0(u) died @p1)
    LDB(bq1, 1, b0); STAGE_A(0, u + 2);
    PHASE_PRE(); MQ(0, 1, bq1); PHASE_POST();
    // p3: q11(u); stage Bh0(u+2) (Bh0(u) died @p1)
    LDA(1, b0); STAGE_B(0, u + 2);
    PHASE_PRE(); MQ(1, 1, bq1); PHASE_POST();
    // p4: q10(u); stage Bh1(u+2) (died @p2); checkpoint covers tile u+1
    STAGE_B(1, u + 2);
    asm volatile("s_waitcnt vmcnt(6)" ::: "memory");
    PHASE_PRE(); MQ(1, 0, bq0); PHASE_POST();
    // p5: q00(u+1); stage Ah1(u+2) (Ah1(u) died @p3)
    LDA(0, b1); LDB(bq0, 0, b1); STAGE_A(1, u + 2);
    PHASE_PRE(); MQ(0, 0, bq0); PHASE_POST();
    // p6: q01(u+1); stage Ah0(u+3)
    LDB(bq1, 1, b1); STAGE_A(0, u + 3);
    PHASE_PRE(); MQ(0, 1, bq1); PHASE_POST();
    // p7: q11(u+1); stage Bh0(u+3)
    LDA(1, b1); STAGE_B(0, u + 3);
    PHASE_PRE(); MQ(1, 1, bq1); PHASE_POST();
    // p8: q10(u+1); stage Bh1(u+3); checkpoint covers tile u+2
    STAGE_B(1, u + 3);
    asm volatile("s_waitcnt vmcnt(6)" ::: "memory");
    PHASE_PRE(); MQ(1, 0, bq0); PHASE_POST();
  }

  // peeled final iteration: u=14, v=15 (no out-of-range stages)
  LDA(0, b0); LDB(bq0, 0, b0); STAGE_A(1, 15);
  PHASE_PRE(); MQ(0, 0, bq0); PHASE_POST();
  LDB(bq1, 1, b0);
  PHASE_PRE(); MQ(0, 1, bq1); PHASE_POST();
  LDA(1, b0);
  PHASE_PRE(); MQ(1, 1, bq1); PHASE_POST();
  asm volatile("s_waitcnt vmcnt(0)" ::: "memory");
  PHASE_PRE(); MQ(1, 0, bq0); PHASE_POST();
  LDA(0, b1); LDB(bq0, 0, b1);
  PHASE_PRE(); MQ(0, 0, bq0); PHASE_POST();
  LDB(bq1, 1, b1);
  PHASE_PRE(); MQ(0, 1, bq1); PHASE_POST();
  LDA(1, b1);
  PHASE_PRE(); MQ(1, 1, bq1); PHASE_POST();
  PHASE_PRE(); MQ(1, 0, bq0); PHASE_POST();

#undef STAGE_A
#undef STAGE_B
#undef LDA
#undef LDB
#undef MQ
#undef PHASE_PRE
#undef PHASE_POST

  // epilogue: C/D layout col=lane&15, row=(lane>>4)*4+reg
  float* Cb = C + ((size_t)batch << 20);
  const int crow0 = brow_t + wr * 128 + lh * 4;
  const int ccol0 = bcol_t + wc * 64 + l4;
#pragma unroll
  for (int m = 0; m < 8; ++m)
#pragma unroll
    for (int n = 0; n < 4; ++n)
#pragma unroll
      for (int r = 0; r < 4; ++r)
        Cb[(size_t)(crow0 + m * 16 + r) * 1024 + ccol0 + n * 16] =
            acc[m][n][r];
}

extern "C" void kernel_launch(void* const* d_in, const int* in_sizes, int n_in,
                              void* d_out, int out_size, void* d_ws, size_t ws_size,
                              hipStream_t stream) {
  const float* a = (const float*)d_in[0];
  const float* b = (const float*)d_in[1];
  const float* w = (const float*)d_in[2];
  float* out = (float*)d_out;

  unsigned short* ra = (unsigned short*)d_ws;                 // 16M bf16
  unsigned short* rb = ra + (size_t)16 * 1024 * 1024;         // 16M bf16

  norm_scale_kernel<<<8192, 256, 0, stream>>>(a, b, w, ra, rb);
  gemm8_kernel<<<256, 512, 0, stream>>>(ra, rb, out);
}